// Round 1
// baseline (7217.820 us; speedup 1.0000x reference)
//
#include <hip/hip_runtime.h>

constexpr int B = 16, S = 512, D = 512, H = 8, DFF = 2048, NL = 4, DK = 64;
constexpr int M = B * S;  // 8192 rows

// ---------------- elementwise: x = q + pe, y = qa + pe ----------------
__global__ __launch_bounds__(256) void add_pe_kernel(
    const float* __restrict__ q, const float* __restrict__ qa,
    const float* __restrict__ pe, float* __restrict__ x, float* __restrict__ y) {
  int idx = blockIdx.x * 256 + threadIdx.x;
  int p = idx & (S * D - 1);  // S*D = 2^18
  float pv = pe[p];
  x[idx] = q[idx] + pv;
  y[idx] = qa[idx] + pv;
}

// ---------------- fp32 GEMM: C = A[M,K] @ W[K,N] + bias, optional ReLU ----------------
// 128x128 tile, BK=8, 256 threads, 8x8 per thread.
template <int RELU>
__global__ __launch_bounds__(256) void gemm_bias(
    const float* __restrict__ A, const float* __restrict__ W,
    const float* __restrict__ bias, float* __restrict__ C,
    int Mm, int N, int K) {
  __shared__ float As[8][132];
  __shared__ float Bs[8][132];
  const int tid = threadIdx.x;
  const int tx = tid & 15;   // n group
  const int ty = tid >> 4;   // m group
  const int arow = blockIdx.y * 128;
  const int bcol = blockIdx.x * 128;

  float acc[8][8];
#pragma unroll
  for (int m = 0; m < 8; m++)
#pragma unroll
    for (int n = 0; n < 8; n++) acc[m][n] = 0.f;

  const int lr = tid >> 1;          // 0..127  (A row within tile)
  const int lk = (tid & 1) * 4;     // 0 or 4  (A k within tile)
  const int wk = tid >> 5;          // 0..7    (W k within tile)
  const int wc = (tid & 31) * 4;    // 0..124  (W col within tile)

  for (int k0 = 0; k0 < K; k0 += 8) {
    float4 a4 = *(const float4*)&A[(size_t)(arow + lr) * K + k0 + lk];
    As[lk + 0][lr] = a4.x;
    As[lk + 1][lr] = a4.y;
    As[lk + 2][lr] = a4.z;
    As[lk + 3][lr] = a4.w;
    float4 b4 = *(const float4*)&W[(size_t)(k0 + wk) * N + bcol + wc];
    *(float4*)&Bs[wk][wc] = b4;
    __syncthreads();
#pragma unroll
    for (int kk = 0; kk < 8; kk++) {
      float af[8], bf[8];
      *(float4*)&af[0] = *(const float4*)&As[kk][ty * 8];
      *(float4*)&af[4] = *(const float4*)&As[kk][ty * 8 + 4];
      *(float4*)&bf[0] = *(const float4*)&Bs[kk][tx * 8];
      *(float4*)&bf[4] = *(const float4*)&Bs[kk][tx * 8 + 4];
#pragma unroll
      for (int m = 0; m < 8; m++)
#pragma unroll
        for (int n = 0; n < 8; n++) acc[m][n] += af[m] * bf[n];
    }
    __syncthreads();
  }

#pragma unroll
  for (int m = 0; m < 8; m++) {
    int row = arow + ty * 8 + m;
#pragma unroll
    for (int n = 0; n < 8; n++) {
      int col = bcol + tx * 8 + n;
      float v = acc[m][n] + bias[col];
      if (RELU) v = fmaxf(v, 0.f);
      C[(size_t)row * N + col] = v;
    }
  }
}

// ---------------- attention: one block per (b,h,i) row ----------------
__global__ __launch_bounds__(256) void attn_kernel(
    const float* __restrict__ qk, const float* __restrict__ v,
    const float* __restrict__ fr, float* __restrict__ out) {
  const int idx = blockIdx.x;        // b*H*S + h*S + i
  const int i = idx & (S - 1);
  const int h = (idx >> 9) & (H - 1);
  const int b = idx >> 12;
  const int t = threadIdx.x;

  __shared__ float qs[DK];
  __shared__ float ss[S];
  __shared__ float red[256];
  __shared__ float outs[4][DK];

  const size_t baseQ = (size_t)(b * S) * D + h * DK;
  float* o = &out[(size_t)(b * S + i) * D + h * DK];

  if (i == 0) {
    if (t < DK) o[t] = 0.f;
    return;
  }
  if (t < DK) qs[t] = qk[baseQ + (size_t)i * D + t];
  __syncthreads();

  const float scale_fr = 0.125f * fr[b * S + i];
  float lmax = -1e30f;
  for (int j = t; j < i; j += 256) {
    const float* qj = &qk[baseQ + (size_t)j * D];
    float dacc = 0.f;
#pragma unroll
    for (int kk = 0; kk < DK; kk++) dacc += qs[kk] * qj[kk];
    dacc *= scale_fr;
    ss[j] = dacc;
    lmax = fmaxf(lmax, dacc);
  }
  red[t] = lmax;
  __syncthreads();
  for (int w = 128; w > 0; w >>= 1) {
    if (t < w) red[t] = fmaxf(red[t], red[t + w]);
    __syncthreads();
  }
  const float mx = red[0];
  __syncthreads();

  float lsum = 0.f;
  for (int j = t; j < i; j += 256) {
    float e = __expf(ss[j] - mx);
    ss[j] = e;
    lsum += e;
  }
  red[t] = lsum;
  __syncthreads();
  for (int w = 128; w > 0; w >>= 1) {
    if (t < w) red[t] += red[t + w];
    __syncthreads();
  }
  const float inv = 1.0f / red[0];
  __syncthreads();

  const int d0 = t & 63;
  const int g = t >> 6;
  float acc = 0.f;
  for (int j = g; j < i; j += 4) acc += ss[j] * v[baseQ + (size_t)j * D + d0];
  outs[g][d0] = acc;
  __syncthreads();
  if (t < DK)
    o[t] = (outs[0][t] + outs[1][t] + outs[2][t] + outs[3][t]) * inv;
}

// ---------------- residual + LayerNorm ----------------
__global__ __launch_bounds__(256) void add_ln_kernel(
    const float* __restrict__ xin, const float* __restrict__ p,
    const float* __restrict__ g, const float* __restrict__ bta,
    float* __restrict__ xout) {
  const int row = blockIdx.x;
  const int t = threadIdx.x;
  __shared__ float red[256];

  float v0 = xin[(size_t)row * D + t] + p[(size_t)row * D + t];
  float v1 = xin[(size_t)row * D + t + 256] + p[(size_t)row * D + t + 256];

  red[t] = v0 + v1;
  __syncthreads();
  for (int w = 128; w > 0; w >>= 1) {
    if (t < w) red[t] += red[t + w];
    __syncthreads();
  }
  const float mu = red[0] * (1.0f / D);
  __syncthreads();

  float d0 = v0 - mu, d1 = v1 - mu;
  red[t] = d0 * d0 + d1 * d1;
  __syncthreads();
  for (int w = 128; w > 0; w >>= 1) {
    if (t < w) red[t] += red[t + w];
    __syncthreads();
  }
  const float rs = rsqrtf(red[0] * (1.0f / D) + 1e-5f);

  xout[(size_t)row * D + t] = d0 * rs * g[t] + bta[t];
  xout[(size_t)row * D + t + 256] = d1 * rs * g[t + 256] + bta[t + 256];
}

extern "C" void kernel_launch(void* const* d_in, const int* in_sizes, int n_in,
                              void* d_out, int out_size, void* d_ws, size_t ws_size,
                              hipStream_t stream) {
  const float* q_embed = (const float*)d_in[0];
  const float* qa_embed = (const float*)d_in[1];
  const float* forget_rate = (const float*)d_in[2];
  const float* pe = (const float*)d_in[3];
  const float* Wk = (const float*)d_in[4];
  const float* bk = (const float*)d_in[5];
  const float* Wv = (const float*)d_in[6];
  const float* bv = (const float*)d_in[7];
  const float* Wo = (const float*)d_in[8];
  const float* bo = (const float*)d_in[9];
  const float* ln1_g = (const float*)d_in[10];
  const float* ln1_b = (const float*)d_in[11];
  const float* W1 = (const float*)d_in[12];
  const float* b1 = (const float*)d_in[13];
  const float* W2 = (const float*)d_in[14];
  const float* b2 = (const float*)d_in[15];
  const float* ln2_g = (const float*)d_in[16];
  const float* ln2_b = (const float*)d_in[17];

  float* ws = (float*)d_ws;
  const size_t nMD = (size_t)M * D;
  float* x = ws;
  float* y = x + nMD;
  float* qk = y + nMD;
  float* vv = qk + nMD;
  float* att = vv + nMD;
  float* proj = att + nMD;
  float* hbuf = proj + nMD;  // M x DFF

  add_pe_kernel<<<(B * S * D) / 256, 256, 0, stream>>>(q_embed, qa_embed, pe, x, y);

  for (int l = 0; l < NL; l++) {
    const float* Wk_l = Wk + (size_t)l * D * D;
    const float* Wv_l = Wv + (size_t)l * D * D;
    const float* Wo_l = Wo + (size_t)l * D * D;
    const float* W1_l = W1 + (size_t)l * D * DFF;
    const float* W2_l = W2 + (size_t)l * DFF * D;

    gemm_bias<0><<<dim3(D / 128, M / 128), 256, 0, stream>>>(x, Wk_l, bk + l * D, qk, M, D, D);
    gemm_bias<0><<<dim3(D / 128, M / 128), 256, 0, stream>>>(y, Wv_l, bv + l * D, vv, M, D, D);
    attn_kernel<<<B * H * S, 256, 0, stream>>>(qk, vv, forget_rate, att);
    gemm_bias<0><<<dim3(D / 128, M / 128), 256, 0, stream>>>(att, Wo_l, bo + l * D, proj, M, D, D);
    add_ln_kernel<<<M, 256, 0, stream>>>(x, proj, ln1_g + l * D, ln1_b + l * D, x);
    gemm_bias<1><<<dim3(DFF / 128, M / 128), 256, 0, stream>>>(x, W1_l, b1 + l * DFF, hbuf, M, DFF, D);
    gemm_bias<0><<<dim3(D / 128, M / 128), 256, 0, stream>>>(hbuf, W2_l, b2 + l * D, proj, M, D, DFF);
    float* xo = (l == NL - 1) ? (float*)d_out : x;
    add_ln_kernel<<<M, 256, 0, stream>>>(x, proj, ln2_g + l * D, ln2_b + l * D, xo);
  }
}

// Round 2
// 688.050 us; speedup vs baseline: 10.4903x; 10.4903x over previous
//
#include <hip/hip_runtime.h>

typedef unsigned short u16;
typedef __attribute__((ext_vector_type(8))) short bh8;   // 8 bf16 in 4 VGPRs
typedef __attribute__((ext_vector_type(4))) float fx4;

constexpr int B = 16, S = 512, D = 512, H = 8, DFF = 2048, NL = 4, DK = 64;
constexpr int M = B * S;  // 8192

__device__ __forceinline__ u16 f2bf(float f) {
  union { float f; unsigned u; } v; v.f = f;
  unsigned r = v.u + 0x7fffu + ((v.u >> 16) & 1u);
  return (u16)(r >> 16);
}

__device__ __forceinline__ void gload16(const void* g, void* l) {
  __builtin_amdgcn_global_load_lds((const __attribute__((address_space(1))) void*)g,
                                   (__attribute__((address_space(3))) void*)l,
                                   16, 0, 0);
}

// ---------------- x = q + pe (f32 + bf16), y = qa + pe (bf16) ----------------
__global__ __launch_bounds__(256) void add_pe(
    const float* __restrict__ q, const float* __restrict__ qa,
    const float* __restrict__ pe, float* __restrict__ x,
    u16* __restrict__ xb, u16* __restrict__ yb) {
  int idx = blockIdx.x * 256 + threadIdx.x;
  float pv = pe[idx & (S * D - 1)];
  float xv = q[idx] + pv, yv = qa[idx] + pv;
  x[idx] = xv;
  xb[idx] = f2bf(xv);
  yb[idx] = f2bf(yv);
}

// ---------------- weight transpose+convert: src f32 [L][K][N] -> dst bf16 [L][N][K] ----------------
__global__ __launch_bounds__(256) void transpose_cvt(
    const float* __restrict__ src, u16* __restrict__ dst, int K, int N) {
  __shared__ float t[64][65];
  const int l = blockIdx.z;
  const int n0 = blockIdx.x * 64, k0 = blockIdx.y * 64;
  const float* s = src + (size_t)l * K * N;
  u16* d = dst + (size_t)l * N * K;
  const int tid = threadIdx.x;
  const int r = tid >> 2, c0 = (tid & 3) * 16;
#pragma unroll
  for (int i = 0; i < 16; i += 4) {
    float4 v = *(const float4*)&s[(size_t)(k0 + r) * N + n0 + c0 + i];
    t[r][c0 + i] = v.x; t[r][c0 + i + 1] = v.y;
    t[r][c0 + i + 2] = v.z; t[r][c0 + i + 3] = v.w;
  }
  __syncthreads();
  u16 tmp[16];
#pragma unroll
  for (int i = 0; i < 16; i++) tmp[i] = f2bf(t[c0 + i][r]);
  *(fx4*)&d[(size_t)(n0 + r) * K + k0 + c0] = *(fx4*)&tmp[0];
  *(fx4*)&d[(size_t)(n0 + r) * K + k0 + c0 + 8] = *(fx4*)&tmp[8];
}

// ---------------- bf16 MFMA GEMM: C[M,N] = A[M,K] @ Wt[N,K]^T + bias ----------------
template <int RELU, int OUTBF>
__global__ __launch_bounds__(256) void gemm_mfma(
    const u16* __restrict__ A, const u16* __restrict__ Wt,
    const float* __restrict__ bias, void* __restrict__ Cout, int N, int K) {
  __shared__ u16 Al[128 * 64];
  __shared__ u16 Bl[128 * 64];
  const int tid = threadIdx.x;
  const int lane = tid & 63, w = tid >> 6;
  const int li = lane & 15, lg = lane >> 4;
  const int arow = blockIdx.y * 128, bcol = blockIdx.x * 128;
  const int wrow = (w >> 1) * 64, wcol = (w & 1) * 64;

  const fx4 zero = {0.f, 0.f, 0.f, 0.f};
  fx4 acc[4][4];
#pragma unroll
  for (int i = 0; i < 4; i++)
#pragma unroll
    for (int j = 0; j < 4; j++) acc[i][j] = zero;

  for (int k0 = 0; k0 < K; k0 += 64) {
#pragma unroll
    for (int p = 0; p < 4; p++) {
      int c = (p * 4 + w) * 64 + lane;
      int r = c >> 3, g = c & 7;
      // LDS linear [128 rows][128B]; global col-group pre-swizzled g^(r&7)
      gload16(&A[(size_t)(arow + r) * K + k0 + ((g ^ (r & 7)) * 8)],
              &Al[(size_t)(p * 4 + w) * 512]);
      gload16(&Wt[(size_t)(bcol + r) * K + k0 + ((g ^ (r & 7)) * 8)],
              &Bl[(size_t)(p * 4 + w) * 512]);
    }
    __syncthreads();
#pragma unroll
    for (int ks = 0; ks < 2; ks++) {
      bh8 am[4], bn[4];
#pragma unroll
      for (int mi = 0; mi < 4; mi++) {
        int r = wrow + mi * 16 + li;
        am[mi] = *(const bh8*)&Al[r * 64 + (((ks * 4 + lg) ^ (r & 7)) * 8)];
      }
#pragma unroll
      for (int ni = 0; ni < 4; ni++) {
        int r = wcol + ni * 16 + li;
        bn[ni] = *(const bh8*)&Bl[r * 64 + (((ks * 4 + lg) ^ (r & 7)) * 8)];
      }
#pragma unroll
      for (int mi = 0; mi < 4; mi++)
#pragma unroll
        for (int ni = 0; ni < 4; ni++)
          acc[mi][ni] = __builtin_amdgcn_mfma_f32_16x16x32_bf16(am[mi], bn[ni], acc[mi][ni], 0, 0, 0);
    }
    __syncthreads();
  }

  float bv[4];
#pragma unroll
  for (int ni = 0; ni < 4; ni++) bv[ni] = bias[bcol + wcol + ni * 16 + li];
#pragma unroll
  for (int mi = 0; mi < 4; mi++)
#pragma unroll
    for (int rr = 0; rr < 4; rr++) {
      int row = arow + wrow + mi * 16 + lg * 4 + rr;
#pragma unroll
      for (int ni = 0; ni < 4; ni++) {
        int col = bcol + wcol + ni * 16 + li;
        float v = acc[mi][ni][rr] + bv[ni];
        if (RELU) v = fmaxf(v, 0.f);
        if (OUTBF) ((u16*)Cout)[(size_t)row * N + col] = f2bf(v);
        else ((float*)Cout)[(size_t)row * N + col] = v;
      }
    }
}

// ---------------- flash attention: scores = (qk qk^T)*scale*fr, strict causal ----------------
__global__ __launch_bounds__(256) void attn_mfma(
    const u16* __restrict__ qk, const u16* __restrict__ vv,
    const float* __restrict__ fr, u16* __restrict__ att) {
  __shared__ u16 Kl[64 * 64];       // swizzled [64 rows][128B]
  __shared__ u16 Vt[64 * 72];       // V^T [d][j], padded rows (144B)
  __shared__ u16 Pl[4][16 * 72];    // per-wave P, padded rows
  const int tid = threadIdx.x;
  const int lane = tid & 63, w = tid >> 6;
  const int li = lane & 15, lg = lane >> 4;
  const int bh = blockIdx.x;
  const int b = bh >> 3, h = bh & 7;
  const int qt = blockIdx.y, qi0 = qt * 64;

  const size_t rowbase = (size_t)(b * S) * D + h * DK;

  bh8 aq[2];
  {
    int qrow = qi0 + w * 16 + li;
#pragma unroll
    for (int ks = 0; ks < 2; ks++)
      aq[ks] = *(const bh8*)&qk[rowbase + (size_t)qrow * D + ks * 32 + lg * 8];
  }
  float frs[4];
#pragma unroll
  for (int rr = 0; rr < 4; rr++)
    frs[rr] = 0.125f * fr[b * S + qi0 + w * 16 + lg * 4 + rr];

  const fx4 zero = {0.f, 0.f, 0.f, 0.f};
  fx4 o_[4];
  float m_[4], l_[4];
#pragma unroll
  for (int i = 0; i < 4; i++) { o_[i] = zero; m_[i] = -1e30f; l_[i] = 0.f; }

  for (int kt = 0; kt <= qt; kt++) {
    // stage K tile (read linear, write swizzled)
#pragma unroll
    for (int p = 0; p < 2; p++) {
      int c = p * 256 + tid;
      int r = c >> 3, g = c & 7;
      fx4 kvv = *(const fx4*)&qk[rowbase + (size_t)(kt * 64 + r) * D + g * 8];
      *(fx4*)&Kl[r * 64 + ((g ^ (r & 7)) * 8)] = kvv;
    }
    // stage V transposed
    {
      int j = tid & 63, d0 = (tid >> 6) * 16;
      u16 tmp[16];
      *(fx4*)&tmp[0] = *(const fx4*)&vv[rowbase + (size_t)(kt * 64 + j) * D + d0];
      *(fx4*)&tmp[8] = *(const fx4*)&vv[rowbase + (size_t)(kt * 64 + j) * D + d0 + 8];
#pragma unroll
      for (int q = 0; q < 16; q++) Vt[(d0 + q) * 72 + j] = tmp[q];
    }
    __syncthreads();

    // QK^T : 16 rows x 64 cols per wave
    fx4 s[4];
#pragma unroll
    for (int jt = 0; jt < 4; jt++) s[jt] = zero;
#pragma unroll
    for (int ks = 0; ks < 2; ks++) {
      bh8 bk[4];
#pragma unroll
      for (int jt = 0; jt < 4; jt++) {
        int r = jt * 16 + li;
        bk[jt] = *(const bh8*)&Kl[r * 64 + (((ks * 4 + lg) ^ (r & 7)) * 8)];
      }
#pragma unroll
      for (int jt = 0; jt < 4; jt++)
        s[jt] = __builtin_amdgcn_mfma_f32_16x16x32_bf16(aq[ks], bk[jt], s[jt], 0, 0, 0);
    }

    const bool diag = (kt == qt);
#pragma unroll
    for (int jt = 0; jt < 4; jt++)
#pragma unroll
      for (int rr = 0; rr < 4; rr++) {
        float sv = s[jt][rr] * frs[rr];
        if (diag && (jt * 16 + li >= w * 16 + lg * 4 + rr)) sv = -1e30f;
        s[jt][rr] = sv;
      }

    // online softmax (rows replicated across the 16 col-lanes)
#pragma unroll
    for (int rr = 0; rr < 4; rr++) {
      float v0 = fmaxf(fmaxf(s[0][rr], s[1][rr]), fmaxf(s[2][rr], s[3][rr]));
      v0 = fmaxf(v0, __shfl_xor(v0, 1));
      v0 = fmaxf(v0, __shfl_xor(v0, 2));
      v0 = fmaxf(v0, __shfl_xor(v0, 4));
      v0 = fmaxf(v0, __shfl_xor(v0, 8));
      float mn = fmaxf(m_[rr], v0);
      float cf = __expf(m_[rr] - mn);
      m_[rr] = mn;
      float ps = 0.f;
#pragma unroll
      for (int jt = 0; jt < 4; jt++) {
        float e = __expf(s[jt][rr] - mn);
        s[jt][rr] = e;
        ps += e;
      }
      ps += __shfl_xor(ps, 1);
      ps += __shfl_xor(ps, 2);
      ps += __shfl_xor(ps, 4);
      ps += __shfl_xor(ps, 8);
      l_[rr] = l_[rr] * cf + ps;
#pragma unroll
      for (int dt = 0; dt < 4; dt++) o_[dt][rr] *= cf;
    }

    // P (C-layout) -> LDS -> A-layout
#pragma unroll
    for (int jt = 0; jt < 4; jt++)
#pragma unroll
      for (int rr = 0; rr < 4; rr++)
        Pl[w][(lg * 4 + rr) * 72 + jt * 16 + li] = f2bf(s[jt][rr]);
    __syncthreads();

#pragma unroll
    for (int ks = 0; ks < 2; ks++) {
      bh8 pa = *(const bh8*)&Pl[w][li * 72 + ks * 32 + lg * 8];
      bh8 bvf[4];
#pragma unroll
      for (int dt = 0; dt < 4; dt++)
        bvf[dt] = *(const bh8*)&Vt[(dt * 16 + li) * 72 + ks * 32 + lg * 8];
#pragma unroll
      for (int dt = 0; dt < 4; dt++)
        o_[dt] = __builtin_amdgcn_mfma_f32_16x16x32_bf16(pa, bvf[dt], o_[dt], 0, 0, 0);
    }
    __syncthreads();
  }

#pragma unroll
  for (int rr = 0; rr < 4; rr++) {
    int rs = qi0 + w * 16 + lg * 4 + rr;
    float inv = (rs == 0) ? 0.f : 1.f / l_[rr];
#pragma unroll
    for (int dt = 0; dt < 4; dt++)
      att[rowbase + (size_t)rs * D + dt * 16 + li] = f2bf(o_[dt][rr] * inv);
  }
}

// ---------------- residual + LayerNorm (f32 master, optional bf16 copy) ----------------
__global__ __launch_bounds__(256) void add_ln(
    const float* __restrict__ xin, const float* __restrict__ p,
    const float* __restrict__ g, const float* __restrict__ bta,
    float* __restrict__ xout, u16* __restrict__ xb) {
  const int row = blockIdx.x;
  const int t = threadIdx.x;
  __shared__ float red[256];

  float v0 = xin[(size_t)row * D + t] + p[(size_t)row * D + t];
  float v1 = xin[(size_t)row * D + t + 256] + p[(size_t)row * D + t + 256];

  red[t] = v0 + v1;
  __syncthreads();
  for (int wd = 128; wd > 0; wd >>= 1) {
    if (t < wd) red[t] += red[t + wd];
    __syncthreads();
  }
  const float mu = red[0] * (1.0f / D);
  __syncthreads();

  float d0 = v0 - mu, d1 = v1 - mu;
  red[t] = d0 * d0 + d1 * d1;
  __syncthreads();
  for (int wd = 128; wd > 0; wd >>= 1) {
    if (t < wd) red[t] += red[t + wd];
    __syncthreads();
  }
  const float rs = rsqrtf(red[0] * (1.0f / D) + 1e-5f);

  float o0 = d0 * rs * g[t] + bta[t];
  float o1 = d1 * rs * g[t + 256] + bta[t + 256];
  xout[(size_t)row * D + t] = o0;
  xout[(size_t)row * D + t + 256] = o1;
  if (xb) {
    xb[(size_t)row * D + t] = f2bf(o0);
    xb[(size_t)row * D + t + 256] = f2bf(o1);
  }
}

extern "C" void kernel_launch(void* const* d_in, const int* in_sizes, int n_in,
                              void* d_out, int out_size, void* d_ws, size_t ws_size,
                              hipStream_t stream) {
  const float* q_embed = (const float*)d_in[0];
  const float* qa_embed = (const float*)d_in[1];
  const float* forget_rate = (const float*)d_in[2];
  const float* pe = (const float*)d_in[3];
  const float* Wk = (const float*)d_in[4];
  const float* bk = (const float*)d_in[5];
  const float* Wv = (const float*)d_in[6];
  const float* bv = (const float*)d_in[7];
  const float* Wo = (const float*)d_in[8];
  const float* bo = (const float*)d_in[9];
  const float* ln1_g = (const float*)d_in[10];
  const float* ln1_b = (const float*)d_in[11];
  const float* W1 = (const float*)d_in[12];
  const float* b1 = (const float*)d_in[13];
  const float* W2 = (const float*)d_in[14];
  const float* b2 = (const float*)d_in[15];
  const float* ln2_g = (const float*)d_in[16];
  const float* ln2_b = (const float*)d_in[17];

  const size_t nMD = (size_t)M * D;
  char* p = (char*)d_ws;
  float* x = (float*)p;      p += nMD * 4;
  float* proj = (float*)p;   p += nMD * 4;
  u16* xb = (u16*)p;         p += nMD * 2;
  u16* yb = (u16*)p;         p += nMD * 2;
  u16* qkb = (u16*)p;        p += nMD * 2;
  u16* vvb = (u16*)p;        p += nMD * 2;
  u16* attb = (u16*)p;       p += nMD * 2;
  u16* hb = (u16*)p;         p += (size_t)M * DFF * 2;
  u16* Wkt = (u16*)p;        p += (size_t)NL * D * D * 2;
  u16* Wvt = (u16*)p;        p += (size_t)NL * D * D * 2;
  u16* Wot = (u16*)p;        p += (size_t)NL * D * D * 2;
  u16* W1t = (u16*)p;        p += (size_t)NL * D * DFF * 2;
  u16* W2t = (u16*)p;        p += (size_t)NL * DFF * D * 2;

  add_pe<<<(B * S * D) / 256, 256, 0, stream>>>(q_embed, qa_embed, pe, x, xb, yb);
  transpose_cvt<<<dim3(D / 64, D / 64, NL), 256, 0, stream>>>(Wk, Wkt, D, D);
  transpose_cvt<<<dim3(D / 64, D / 64, NL), 256, 0, stream>>>(Wv, Wvt, D, D);
  transpose_cvt<<<dim3(D / 64, D / 64, NL), 256, 0, stream>>>(Wo, Wot, D, D);
  transpose_cvt<<<dim3(DFF / 64, D / 64, NL), 256, 0, stream>>>(W1, W1t, D, DFF);
  transpose_cvt<<<dim3(D / 64, DFF / 64, NL), 256, 0, stream>>>(W2, W2t, DFF, D);

  for (int l = 0; l < NL; l++) {
    gemm_mfma<0, 1><<<dim3(D / 128, M / 128), 256, 0, stream>>>(
        xb, Wkt + (size_t)l * D * D, bk + l * D, qkb, D, D);
    gemm_mfma<0, 1><<<dim3(D / 128, M / 128), 256, 0, stream>>>(
        yb, Wvt + (size_t)l * D * D, bv + l * D, vvb, D, D);
    attn_mfma<<<dim3(B * H, S / 64), 256, 0, stream>>>(qkb, vvb, forget_rate, attb);
    gemm_mfma<0, 0><<<dim3(D / 128, M / 128), 256, 0, stream>>>(
        attb, Wot + (size_t)l * D * D, bo + l * D, proj, D, D);
    add_ln<<<M, 256, 0, stream>>>(x, proj, ln1_g + l * D, ln1_b + l * D, x, xb);
    gemm_mfma<1, 1><<<dim3(DFF / 128, M / 128), 256, 0, stream>>>(
        xb, W1t + (size_t)l * D * DFF, b1 + l * DFF, hb, DFF, D);
    gemm_mfma<0, 0><<<dim3(D / 128, M / 128), 256, 0, stream>>>(
        hb, W2t + (size_t)l * DFF * D, b2 + l * D, proj, D, DFF);
    float* xo = (l == NL - 1) ? (float*)d_out : x;
    u16* xbo = (l == NL - 1) ? (u16*)nullptr : xb;
    add_ln<<<M, 256, 0, stream>>>(x, proj, ln2_g + l * D, ln2_b + l * D, xo, xbo);
  }
}

// Round 4
// 555.034 us; speedup vs baseline: 13.0043x; 1.2397x over previous
//
#include <hip/hip_runtime.h>

typedef unsigned short u16;
typedef __attribute__((ext_vector_type(8))) short bh8;   // 8 bf16 in 4 VGPRs
typedef __attribute__((ext_vector_type(4))) short sh4;   // 4 bf16 = 8B
typedef __attribute__((ext_vector_type(4))) float fx4;

constexpr int B = 16, S = 512, D = 512, H = 8, DFF = 2048, NL = 4, DK = 64;
constexpr int M = B * S;  // 8192

__device__ __forceinline__ u16 f2bf(float f) {
  union { float f; unsigned u; } v; v.f = f;
  unsigned r = v.u + 0x7fffu + ((v.u >> 16) & 1u);
  return (u16)(r >> 16);
}

__device__ __forceinline__ void gload16(const void* g, void* l) {
  __builtin_amdgcn_global_load_lds((const __attribute__((address_space(1))) void*)g,
                                   (__attribute__((address_space(3))) void*)l,
                                   16, 0, 0);
}

// ---------------- x = q + pe (f32 + bf16), y = qa + pe (bf16) ----------------
__global__ __launch_bounds__(256) void add_pe(
    const float* __restrict__ q, const float* __restrict__ qa,
    const float* __restrict__ pe, float* __restrict__ x,
    u16* __restrict__ xb, u16* __restrict__ yb) {
  int idx = blockIdx.x * 256 + threadIdx.x;
  float pv = pe[idx & (S * D - 1)];
  float xv = q[idx] + pv, yv = qa[idx] + pv;
  x[idx] = xv;
  xb[idx] = f2bf(xv);
  yb[idx] = f2bf(yv);
}

// ---------------- weight transpose+convert: src f32 [L][K][N] -> dst bf16 [L][N][K] ----------------
__global__ __launch_bounds__(256) void transpose_cvt(
    const float* __restrict__ src, u16* __restrict__ dst, int K, int N) {
  __shared__ float t[64][65];
  const int l = blockIdx.z;
  const int n0 = blockIdx.x * 64, k0 = blockIdx.y * 64;
  const float* s = src + (size_t)l * K * N;
  u16* d = dst + (size_t)l * N * K;
  const int tid = threadIdx.x;
  const int r = tid >> 2, c0 = (tid & 3) * 16;
#pragma unroll
  for (int i = 0; i < 16; i += 4) {
    float4 v = *(const float4*)&s[(size_t)(k0 + r) * N + n0 + c0 + i];
    t[r][c0 + i] = v.x; t[r][c0 + i + 1] = v.y;
    t[r][c0 + i + 2] = v.z; t[r][c0 + i + 3] = v.w;
  }
  __syncthreads();
  u16 tmp[16];
#pragma unroll
  for (int i = 0; i < 16; i++) tmp[i] = f2bf(t[c0 + i][r]);
  *(fx4*)&d[(size_t)(n0 + r) * K + k0 + c0] = *(fx4*)&tmp[0];
  *(fx4*)&d[(size_t)(n0 + r) * K + k0 + c0 + 8] = *(fx4*)&tmp[8];
}

// ---------------- bf16 MFMA GEMM core: C[M,N] = A[M,K] @ Wt[N,K]^T + bias ----------------
// 2-phase double-buffered: stage(next) -> compute(cur) -> syncthreads.
template <int BM, int BN, int RELU, int OUTBF>
__device__ __forceinline__ void gemm_core(
    const u16* __restrict__ A, const u16* __restrict__ Wt,
    const float* __restrict__ bias, void* __restrict__ Cout,
    int N, int K, int ntn, u16* Al, u16* Bl) {
  const int tid = threadIdx.x;
  const int lane = tid & 63, w = tid >> 6;
  const int li = lane & 15, lg = lane >> 4;

  // bijective XCD swizzle (gridDim.x % 8 == 0), m-major tile space
  const int cpx = gridDim.x >> 3;
  const int bid = blockIdx.x;
  const int swz = (bid & 7) * cpx + (bid >> 3);
  const int mt = swz / ntn, nt = swz % ntn;
  const int arow = mt * BM, bcol = nt * BN;

  const int wrow = (w >> 1) * (BM / 2), wcol = (w & 1) * (BN / 2);
  constexpr int MR = BM / 32, NR = BN / 32;
  constexpr int ACH = (BM * 8) / 256, BCH = (BN * 8) / 256;
  constexpr int ABUF = BM * 64, BBUF = BN * 64;

  const fx4 zero = {0.f, 0.f, 0.f, 0.f};
  fx4 acc[MR][NR];
#pragma unroll
  for (int i = 0; i < MR; i++)
#pragma unroll
    for (int j = 0; j < NR; j++) acc[i][j] = zero;

  auto stage = [&](int buf, int k0) {
#pragma unroll
    for (int i = 0; i < ACH; i++) {
      int c = i * 256 + tid, r = c >> 3, g = c & 7;
      gload16(&A[(size_t)(arow + r) * K + k0 + ((g ^ (r & 7)) << 3)],
              &Al[buf * ABUF + (i * 4 + w) * 512]);
    }
#pragma unroll
    for (int i = 0; i < BCH; i++) {
      int c = i * 256 + tid, r = c >> 3, g = c & 7;
      gload16(&Wt[(size_t)(bcol + r) * K + k0 + ((g ^ (r & 7)) << 3)],
              &Bl[buf * BBUF + (i * 4 + w) * 512]);
    }
  };
  auto compute = [&](int buf) {
#pragma unroll
    for (int ks = 0; ks < 2; ks++) {
      bh8 am[MR], bn[NR];
#pragma unroll
      for (int mi = 0; mi < MR; mi++) {
        int r = wrow + mi * 16 + li;
        am[mi] = *(const bh8*)&Al[buf * ABUF + r * 64 + (((ks * 4 + lg) ^ (r & 7)) << 3)];
      }
#pragma unroll
      for (int ni = 0; ni < NR; ni++) {
        int r = wcol + ni * 16 + li;
        bn[ni] = *(const bh8*)&Bl[buf * BBUF + r * 64 + (((ks * 4 + lg) ^ (r & 7)) << 3)];
      }
#pragma unroll
      for (int mi = 0; mi < MR; mi++)
#pragma unroll
        for (int ni = 0; ni < NR; ni++)
          acc[mi][ni] = __builtin_amdgcn_mfma_f32_16x16x32_bf16(am[mi], bn[ni], acc[mi][ni], 0, 0, 0);
    }
  };

  stage(0, 0);
  __syncthreads();
  const int nk = K >> 6;
  int cur = 0;
  for (int t = 0; t < nk - 1; t++) {
    stage(cur ^ 1, (t + 1) << 6);
    compute(cur);
    __syncthreads();
    cur ^= 1;
  }
  compute(cur);

  float bv[NR];
#pragma unroll
  for (int ni = 0; ni < NR; ni++) bv[ni] = bias[bcol + wcol + ni * 16 + li];
#pragma unroll
  for (int mi = 0; mi < MR; mi++)
#pragma unroll
    for (int rr = 0; rr < 4; rr++) {
      int row = arow + wrow + mi * 16 + lg * 4 + rr;
#pragma unroll
      for (int ni = 0; ni < NR; ni++) {
        int col = bcol + wcol + ni * 16 + li;
        float v = acc[mi][ni][rr] + bv[ni];
        if (RELU) v = fmaxf(v, 0.f);
        if (OUTBF) ((u16*)Cout)[(size_t)row * N + col] = f2bf(v);
        else ((float*)Cout)[(size_t)row * N + col] = v;
      }
    }
}

template <int BM, int BN, int RELU, int OUTBF>
__global__ __launch_bounds__(256) void gemm2(
    const u16* __restrict__ A, const u16* __restrict__ Wt,
    const float* __restrict__ bias, void* __restrict__ Cout, int N, int K, int ntn) {
  __shared__ u16 Al[2 * BM * 64];
  __shared__ u16 Bl[2 * BN * 64];
  gemm_core<BM, BN, RELU, OUTBF>(A, Wt, bias, Cout, N, K, ntn, Al, Bl);
}

// fused QK + V projections (independent GEMMs selected by blockIdx.y)
__global__ __launch_bounds__(256) void gemm2_dual(
    const u16* __restrict__ A0, const u16* __restrict__ W0,
    const float* __restrict__ b0, u16* __restrict__ C0,
    const u16* __restrict__ A1, const u16* __restrict__ W1,
    const float* __restrict__ b1, u16* __restrict__ C1, int N, int K, int ntn) {
  __shared__ u16 Al[2 * 64 * 64];
  __shared__ u16 Bl[2 * 128 * 64];
  const u16* A = blockIdx.y ? A1 : A0;
  const u16* Wt = blockIdx.y ? W1 : W0;
  const float* bias = blockIdx.y ? b1 : b0;
  u16* C = blockIdx.y ? C1 : C0;
  gemm_core<64, 128, 0, 1>(A, Wt, bias, C, N, K, ntn, Al, Bl);
}

// ---------------- flash attention: scores = (qk qk^T)*scale*fr, strict causal ----------------
__global__ __launch_bounds__(256) void attn_mfma(
    const u16* __restrict__ qk, const u16* __restrict__ vv,
    const float* __restrict__ fr, u16* __restrict__ att) {
  __shared__ u16 Kl[64 * 64];       // swizzled [64 rows][128B]
  __shared__ u16 Vt[64 * 72];       // V^T [d][j], padded rows
  __shared__ u16 Pl[4][16 * 72];    // per-wave P, padded rows
  const int tid = threadIdx.x;
  const int lane = tid & 63, w = tid >> 6;
  const int li = lane & 15, lg = lane >> 4;
  const int bh = blockIdx.x;
  const int b = bh >> 3, h = bh & 7;
  const int qt = blockIdx.y, qi0 = qt * 64;

  const size_t rowbase = (size_t)(b * S) * D + h * DK;

  bh8 aq[2];
  {
    int qrow = qi0 + w * 16 + li;
#pragma unroll
    for (int ks = 0; ks < 2; ks++)
      aq[ks] = *(const bh8*)&qk[rowbase + (size_t)qrow * D + ks * 32 + lg * 8];
  }
  float frs[4];
#pragma unroll
  for (int rr = 0; rr < 4; rr++)
    frs[rr] = 0.125f * fr[b * S + qi0 + w * 16 + lg * 4 + rr];

  const fx4 zero = {0.f, 0.f, 0.f, 0.f};
  fx4 o_[4];
  float m_[4], l_[4];
#pragma unroll
  for (int i = 0; i < 4; i++) { o_[i] = zero; m_[i] = -1e30f; l_[i] = 0.f; }

  for (int kt = 0; kt <= qt; kt++) {
#pragma unroll
    for (int p = 0; p < 2; p++) {
      int c = p * 256 + tid;
      int r = c >> 3, g = c & 7;
      fx4 kvv = *(const fx4*)&qk[rowbase + (size_t)(kt * 64 + r) * D + g * 8];
      *(fx4*)&Kl[r * 64 + ((g ^ (r & 7)) * 8)] = kvv;
    }
    {
      int j = tid & 63, d0 = (tid >> 6) * 16;
      u16 tmp[16];
      *(fx4*)&tmp[0] = *(const fx4*)&vv[rowbase + (size_t)(kt * 64 + j) * D + d0];
      *(fx4*)&tmp[8] = *(const fx4*)&vv[rowbase + (size_t)(kt * 64 + j) * D + d0 + 8];
#pragma unroll
      for (int q = 0; q < 16; q++) Vt[(d0 + q) * 72 + j] = tmp[q];
    }
    __syncthreads();

    fx4 s[4];
#pragma unroll
    for (int jt = 0; jt < 4; jt++) s[jt] = zero;
#pragma unroll
    for (int ks = 0; ks < 2; ks++) {
      bh8 bk[4];
#pragma unroll
      for (int jt = 0; jt < 4; jt++) {
        int r = jt * 16 + li;
        bk[jt] = *(const bh8*)&Kl[r * 64 + (((ks * 4 + lg) ^ (r & 7)) * 8)];
      }
#pragma unroll
      for (int jt = 0; jt < 4; jt++)
        s[jt] = __builtin_amdgcn_mfma_f32_16x16x32_bf16(aq[ks], bk[jt], s[jt], 0, 0, 0);
    }

    const bool diag = (kt == qt);
#pragma unroll
    for (int jt = 0; jt < 4; jt++)
#pragma unroll
      for (int rr = 0; rr < 4; rr++) {
        float sv = s[jt][rr] * frs[rr];
        if (diag && (jt * 16 + li >= w * 16 + lg * 4 + rr)) sv = -1e30f;
        s[jt][rr] = sv;
      }

#pragma unroll
    for (int rr = 0; rr < 4; rr++) {
      float v0 = fmaxf(fmaxf(s[0][rr], s[1][rr]), fmaxf(s[2][rr], s[3][rr]));
      v0 = fmaxf(v0, __shfl_xor(v0, 1));
      v0 = fmaxf(v0, __shfl_xor(v0, 2));
      v0 = fmaxf(v0, __shfl_xor(v0, 4));
      v0 = fmaxf(v0, __shfl_xor(v0, 8));
      float mn = fmaxf(m_[rr], v0);
      float cf = __expf(m_[rr] - mn);
      m_[rr] = mn;
      float ps = 0.f;
#pragma unroll
      for (int jt = 0; jt < 4; jt++) {
        float e = __expf(s[jt][rr] - mn);
        s[jt][rr] = e;
        ps += e;
      }
      ps += __shfl_xor(ps, 1);
      ps += __shfl_xor(ps, 2);
      ps += __shfl_xor(ps, 4);
      ps += __shfl_xor(ps, 8);
      l_[rr] = l_[rr] * cf + ps;
#pragma unroll
      for (int dt = 0; dt < 4; dt++) o_[dt][rr] *= cf;
    }

#pragma unroll
    for (int jt = 0; jt < 4; jt++)
#pragma unroll
      for (int rr = 0; rr < 4; rr++)
        Pl[w][(lg * 4 + rr) * 72 + jt * 16 + li] = f2bf(s[jt][rr]);
    __syncthreads();

#pragma unroll
    for (int ks = 0; ks < 2; ks++) {
      bh8 pa = *(const bh8*)&Pl[w][li * 72 + ks * 32 + lg * 8];
      bh8 bvf[4];
#pragma unroll
      for (int dt = 0; dt < 4; dt++)
        bvf[dt] = *(const bh8*)&Vt[(dt * 16 + li) * 72 + ks * 32 + lg * 8];
#pragma unroll
      for (int dt = 0; dt < 4; dt++)
        o_[dt] = __builtin_amdgcn_mfma_f32_16x16x32_bf16(pa, bvf[dt], o_[dt], 0, 0, 0);
    }
    __syncthreads();
  }

#pragma unroll
  for (int rr = 0; rr < 4; rr++) {
    int rs = qi0 + w * 16 + lg * 4 + rr;
    float inv = (rs == 0) ? 0.f : 1.f / l_[rr];
#pragma unroll
    for (int dt = 0; dt < 4; dt++)
      att[rowbase + (size_t)rs * D + dt * 16 + li] = f2bf(o_[dt][rr] * inv);
  }
}

// ---------------- residual + LayerNorm (wave per row, 4 rows/block) ----------------
__global__ __launch_bounds__(256) void add_ln(
    const float* __restrict__ xin, const float* __restrict__ p,
    const float* __restrict__ g, const float* __restrict__ bta,
    float* __restrict__ xout, u16* __restrict__ xb) {
  const int w = threadIdx.x >> 6, lane = threadIdx.x & 63;
  const int row = blockIdx.x * 4 + w;
  const float* xi = &xin[(size_t)row * D];
  const float* pp = &p[(size_t)row * D];

  float4 u0 = *(const float4*)&xi[lane * 4];
  float4 q0 = *(const float4*)&pp[lane * 4];
  float4 u1 = *(const float4*)&xi[256 + lane * 4];
  float4 q1 = *(const float4*)&pp[256 + lane * 4];
  float v[8] = {u0.x + q0.x, u0.y + q0.y, u0.z + q0.z, u0.w + q0.w,
                u1.x + q1.x, u1.y + q1.y, u1.z + q1.z, u1.w + q1.w};

  float s = 0.f;
#pragma unroll
  for (int i = 0; i < 8; i++) s += v[i];
#pragma unroll
  for (int d = 1; d < 64; d <<= 1) s += __shfl_xor(s, d);
  const float mu = s * (1.0f / D);

  float vs = 0.f;
#pragma unroll
  for (int i = 0; i < 8; i++) { v[i] -= mu; vs += v[i] * v[i]; }
#pragma unroll
  for (int d = 1; d < 64; d <<= 1) vs += __shfl_xor(vs, d);
  const float rs = rsqrtf(vs * (1.0f / D) + 1e-5f);

  float4 g0 = *(const float4*)&g[lane * 4];
  float4 b0 = *(const float4*)&bta[lane * 4];
  float4 g1 = *(const float4*)&g[256 + lane * 4];
  float4 b1 = *(const float4*)&bta[256 + lane * 4];
  float o[8];
  o[0] = v[0] * rs * g0.x + b0.x; o[1] = v[1] * rs * g0.y + b0.y;
  o[2] = v[2] * rs * g0.z + b0.z; o[3] = v[3] * rs * g0.w + b0.w;
  o[4] = v[4] * rs * g1.x + b1.x; o[5] = v[5] * rs * g1.y + b1.y;
  o[6] = v[6] * rs * g1.z + b1.z; o[7] = v[7] * rs * g1.w + b1.w;

  *(float4*)&xout[(size_t)row * D + lane * 4] = *(float4*)&o[0];
  *(float4*)&xout[(size_t)row * D + 256 + lane * 4] = *(float4*)&o[4];
  if (xb) {
    u16 ob[8];
#pragma unroll
    for (int i = 0; i < 8; i++) ob[i] = f2bf(o[i]);
    // two 8B stores at the CORRECT offsets (o[0..3] -> lane*4, o[4..7] -> 256+lane*4)
    *(sh4*)&xb[(size_t)row * D + lane * 4] = *(sh4*)&ob[0];
    *(sh4*)&xb[(size_t)row * D + 256 + lane * 4] = *(sh4*)&ob[4];
  }
}

extern "C" void kernel_launch(void* const* d_in, const int* in_sizes, int n_in,
                              void* d_out, int out_size, void* d_ws, size_t ws_size,
                              hipStream_t stream) {
  const float* q_embed = (const float*)d_in[0];
  const float* qa_embed = (const float*)d_in[1];
  const float* forget_rate = (const float*)d_in[2];
  const float* pe = (const float*)d_in[3];
  const float* Wk = (const float*)d_in[4];
  const float* bk = (const float*)d_in[5];
  const float* Wv = (const float*)d_in[6];
  const float* bv = (const float*)d_in[7];
  const float* Wo = (const float*)d_in[8];
  const float* bo = (const float*)d_in[9];
  const float* ln1_g = (const float*)d_in[10];
  const float* ln1_b = (const float*)d_in[11];
  const float* W1 = (const float*)d_in[12];
  const float* b1 = (const float*)d_in[13];
  const float* W2 = (const float*)d_in[14];
  const float* b2 = (const float*)d_in[15];
  const float* ln2_g = (const float*)d_in[16];
  const float* ln2_b = (const float*)d_in[17];

  const size_t nMD = (size_t)M * D;
  char* p = (char*)d_ws;
  float* x = (float*)p;      p += nMD * 4;
  float* proj = (float*)p;   p += nMD * 4;
  u16* xb = (u16*)p;         p += nMD * 2;
  u16* yb = (u16*)p;         p += nMD * 2;
  u16* qkb = (u16*)p;        p += nMD * 2;
  u16* vvb = (u16*)p;        p += nMD * 2;
  u16* attb = (u16*)p;       p += nMD * 2;
  u16* hb = (u16*)p;         p += (size_t)M * DFF * 2;
  u16* Wkt = (u16*)p;        p += (size_t)NL * D * D * 2;
  u16* Wvt = (u16*)p;        p += (size_t)NL * D * D * 2;
  u16* Wot = (u16*)p;        p += (size_t)NL * D * D * 2;
  u16* W1t = (u16*)p;        p += (size_t)NL * D * DFF * 2;
  u16* W2t = (u16*)p;        p += (size_t)NL * DFF * D * 2;

  add_pe<<<(B * S * D) / 256, 256, 0, stream>>>(q_embed, qa_embed, pe, x, xb, yb);
  transpose_cvt<<<dim3(D / 64, D / 64, NL), 256, 0, stream>>>(Wk, Wkt, D, D);
  transpose_cvt<<<dim3(D / 64, D / 64, NL), 256, 0, stream>>>(Wv, Wvt, D, D);
  transpose_cvt<<<dim3(D / 64, D / 64, NL), 256, 0, stream>>>(Wo, Wot, D, D);
  transpose_cvt<<<dim3(DFF / 64, D / 64, NL), 256, 0, stream>>>(W1, W1t, D, DFF);
  transpose_cvt<<<dim3(D / 64, DFF / 64, NL), 256, 0, stream>>>(W2, W2t, DFF, D);

  const int gD = (M / 64) * (D / 128);     // 512
  const int gF = (M / 64) * (DFF / 128);   // 2048

  for (int l = 0; l < NL; l++) {
    gemm2_dual<<<dim3(gD, 2), 256, 0, stream>>>(
        xb, Wkt + (size_t)l * D * D, bk + l * D, qkb,
        yb, Wvt + (size_t)l * D * D, bv + l * D, vvb, D, D, D / 128);
    attn_mfma<<<dim3(B * H, S / 64), 256, 0, stream>>>(qkb, vvb, forget_rate, attb);
    gemm2<64, 128, 0, 0><<<gD, 256, 0, stream>>>(
        attb, Wot + (size_t)l * D * D, bo + l * D, proj, D, D, D / 128);
    add_ln<<<M / 4, 256, 0, stream>>>(x, proj, ln1_g + l * D, ln1_b + l * D, x, xb);
    gemm2<64, 128, 1, 1><<<gF, 256, 0, stream>>>(
        xb, W1t + (size_t)l * D * DFF, b1 + l * DFF, hb, DFF, D, DFF / 128);
    gemm2<64, 128, 0, 0><<<gD, 256, 0, stream>>>(
        hb, W2t + (size_t)l * DFF * D, b2 + l * D, proj, D, DFF, D / 128);
    float* xo = (l == NL - 1) ? (float*)d_out : x;
    u16* xbo = (l == NL - 1) ? (u16*)nullptr : xb;
    add_ln<<<M / 4, 256, 0, stream>>>(x, proj, ln2_g + l * D, ln2_b + l * D, xo, xbo);
  }
}

// Round 5
// 550.577 us; speedup vs baseline: 13.1096x; 1.0081x over previous
//
#include <hip/hip_runtime.h>

typedef unsigned short u16;
typedef __attribute__((ext_vector_type(8))) short bh8;   // 8 bf16 in 4 VGPRs
typedef __attribute__((ext_vector_type(4))) short sh4;   // 4 bf16 = 8B
typedef __attribute__((ext_vector_type(4))) float fx4;

constexpr int B = 16, S = 512, D = 512, H = 8, DFF = 2048, NL = 4, DK = 64;
constexpr int M = B * S;  // 8192

__device__ __forceinline__ u16 f2bf(float f) {
  union { float f; unsigned u; } v; v.f = f;
  unsigned r = v.u + 0x7fffu + ((v.u >> 16) & 1u);
  return (u16)(r >> 16);
}
__device__ __forceinline__ float bf2f(u16 b) {
  union { unsigned u; float f; } v; v.u = ((unsigned)b) << 16;
  return v.f;
}

__device__ __forceinline__ void gload16(const void* g, void* l) {
  __builtin_amdgcn_global_load_lds((const __attribute__((address_space(1))) void*)g,
                                   (__attribute__((address_space(3))) void*)l,
                                   16, 0, 0);
}

// ---------------- x = q + pe (f32 + bf16), y = qa + pe (bf16) ----------------
__global__ __launch_bounds__(256) void add_pe(
    const float* __restrict__ q, const float* __restrict__ qa,
    const float* __restrict__ pe, float* __restrict__ x,
    u16* __restrict__ xb, u16* __restrict__ yb) {
  int idx = blockIdx.x * 256 + threadIdx.x;
  float pv = pe[idx & (S * D - 1)];
  float xv = q[idx] + pv, yv = qa[idx] + pv;
  x[idx] = xv;
  xb[idx] = f2bf(xv);
  yb[idx] = f2bf(yv);
}

// ---------------- weight transpose+convert: src f32 [L][K][N] -> dst bf16 [L][N][K] ----------------
__global__ __launch_bounds__(256) void transpose_cvt(
    const float* __restrict__ src, u16* __restrict__ dst, int K, int N) {
  __shared__ float t[64][65];
  const int l = blockIdx.z;
  const int n0 = blockIdx.x * 64, k0 = blockIdx.y * 64;
  const float* s = src + (size_t)l * K * N;
  u16* d = dst + (size_t)l * N * K;
  const int tid = threadIdx.x;
  const int r = tid >> 2, c0 = (tid & 3) * 16;
#pragma unroll
  for (int i = 0; i < 16; i += 4) {
    float4 v = *(const float4*)&s[(size_t)(k0 + r) * N + n0 + c0 + i];
    t[r][c0 + i] = v.x; t[r][c0 + i + 1] = v.y;
    t[r][c0 + i + 2] = v.z; t[r][c0 + i + 3] = v.w;
  }
  __syncthreads();
  u16 tmp[16];
#pragma unroll
  for (int i = 0; i < 16; i++) tmp[i] = f2bf(t[c0 + i][r]);
  *(fx4*)&d[(size_t)(n0 + r) * K + k0 + c0] = *(fx4*)&tmp[0];
  *(fx4*)&d[(size_t)(n0 + r) * K + k0 + c0 + 8] = *(fx4*)&tmp[8];
}

// ---------------- bf16 MFMA GEMM core: C[M,N] = A[M,K] @ Wt[N,K]^T + bias ----------------
// 2-phase double-buffered: stage(next) -> compute(cur) -> syncthreads.
template <int BM, int BN, int RELU, int OUTBF>
__device__ __forceinline__ void gemm_core(
    const u16* __restrict__ A, const u16* __restrict__ Wt,
    const float* __restrict__ bias, void* __restrict__ Cout,
    int N, int K, int ntn, u16* Al, u16* Bl) {
  const int tid = threadIdx.x;
  const int lane = tid & 63, w = tid >> 6;
  const int li = lane & 15, lg = lane >> 4;

  // bijective XCD swizzle (gridDim.x % 8 == 0), m-major tile space
  const int cpx = gridDim.x >> 3;
  const int bid = blockIdx.x;
  const int swz = (bid & 7) * cpx + (bid >> 3);
  const int mt = swz / ntn, nt = swz % ntn;
  const int arow = mt * BM, bcol = nt * BN;

  const int wrow = (w >> 1) * (BM / 2), wcol = (w & 1) * (BN / 2);
  constexpr int MR = BM / 32, NR = BN / 32;
  constexpr int ACH = (BM * 8) / 256, BCH = (BN * 8) / 256;
  constexpr int ABUF = BM * 64, BBUF = BN * 64;

  const fx4 zero = {0.f, 0.f, 0.f, 0.f};
  fx4 acc[MR][NR];
#pragma unroll
  for (int i = 0; i < MR; i++)
#pragma unroll
    for (int j = 0; j < NR; j++) acc[i][j] = zero;

  auto stage = [&](int buf, int k0) {
#pragma unroll
    for (int i = 0; i < ACH; i++) {
      int c = i * 256 + tid, r = c >> 3, g = c & 7;
      gload16(&A[(size_t)(arow + r) * K + k0 + ((g ^ (r & 7)) << 3)],
              &Al[buf * ABUF + (i * 4 + w) * 512]);
    }
#pragma unroll
    for (int i = 0; i < BCH; i++) {
      int c = i * 256 + tid, r = c >> 3, g = c & 7;
      gload16(&Wt[(size_t)(bcol + r) * K + k0 + ((g ^ (r & 7)) << 3)],
              &Bl[buf * BBUF + (i * 4 + w) * 512]);
    }
  };
  auto compute = [&](int buf) {
#pragma unroll
    for (int ks = 0; ks < 2; ks++) {
      bh8 am[MR], bn[NR];
#pragma unroll
      for (int mi = 0; mi < MR; mi++) {
        int r = wrow + mi * 16 + li;
        am[mi] = *(const bh8*)&Al[buf * ABUF + r * 64 + (((ks * 4 + lg) ^ (r & 7)) << 3)];
      }
#pragma unroll
      for (int ni = 0; ni < NR; ni++) {
        int r = wcol + ni * 16 + li;
        bn[ni] = *(const bh8*)&Bl[buf * BBUF + r * 64 + (((ks * 4 + lg) ^ (r & 7)) << 3)];
      }
#pragma unroll
      for (int mi = 0; mi < MR; mi++)
#pragma unroll
        for (int ni = 0; ni < NR; ni++)
          acc[mi][ni] = __builtin_amdgcn_mfma_f32_16x16x32_bf16(am[mi], bn[ni], acc[mi][ni], 0, 0, 0);
    }
  };

  stage(0, 0);
  __syncthreads();
  const int nk = K >> 6;
  int cur = 0;
  for (int t = 0; t < nk - 1; t++) {
    stage(cur ^ 1, (t + 1) << 6);
    compute(cur);
    __syncthreads();
    cur ^= 1;
  }
  compute(cur);

  float bv[NR];
#pragma unroll
  for (int ni = 0; ni < NR; ni++) bv[ni] = bias[bcol + wcol + ni * 16 + li];
#pragma unroll
  for (int mi = 0; mi < MR; mi++)
#pragma unroll
    for (int rr = 0; rr < 4; rr++) {
      int row = arow + wrow + mi * 16 + lg * 4 + rr;
#pragma unroll
      for (int ni = 0; ni < NR; ni++) {
        int col = bcol + wcol + ni * 16 + li;
        float v = acc[mi][ni][rr] + bv[ni];
        if (RELU) v = fmaxf(v, 0.f);
        if (OUTBF) ((u16*)Cout)[(size_t)row * N + col] = f2bf(v);
        else ((float*)Cout)[(size_t)row * N + col] = v;
      }
    }
}

template <int BM, int BN, int RELU, int OUTBF>
__global__ __launch_bounds__(256) void gemm2(
    const u16* __restrict__ A, const u16* __restrict__ Wt,
    const float* __restrict__ bias, void* __restrict__ Cout, int N, int K, int ntn) {
  __shared__ u16 Al[2 * BM * 64];
  __shared__ u16 Bl[2 * BN * 64];
  gemm_core<BM, BN, RELU, OUTBF>(A, Wt, bias, Cout, N, K, ntn, Al, Bl);
}

// fused QK + V projections (independent GEMMs selected by blockIdx.y)
__global__ __launch_bounds__(256) void gemm2_dual(
    const u16* __restrict__ A0, const u16* __restrict__ W0,
    const float* __restrict__ b0, u16* __restrict__ C0,
    const u16* __restrict__ A1, const u16* __restrict__ W1,
    const float* __restrict__ b1, u16* __restrict__ C1, int N, int K, int ntn) {
  __shared__ u16 Al[2 * 64 * 64];
  __shared__ u16 Bl[2 * 128 * 64];
  const u16* A = blockIdx.y ? A1 : A0;
  const u16* Wt = blockIdx.y ? W1 : W0;
  const float* bias = blockIdx.y ? b1 : b0;
  u16* C = blockIdx.y ? C1 : C0;
  gemm_core<64, 128, 0, 1>(A, Wt, bias, C, N, K, ntn, Al, Bl);
}

// ---------------- flash attention: scores = (qk qk^T)*scale*fr, strict causal ----------------
__global__ __launch_bounds__(256) void attn_mfma(
    const u16* __restrict__ qk, const u16* __restrict__ vv,
    const float* __restrict__ fr, u16* __restrict__ att) {
  __shared__ u16 Kl[64 * 64];       // swizzled [64 rows][128B]
  __shared__ u16 Vt[64 * 72];       // V^T [d][j], padded rows
  __shared__ u16 Pl[4][16 * 72];    // per-wave P, padded rows
  const int tid = threadIdx.x;
  const int lane = tid & 63, w = tid >> 6;
  const int li = lane & 15, lg = lane >> 4;
  const int bh = blockIdx.x;
  const int b = bh >> 3, h = bh & 7;
  const int qt = blockIdx.y, qi0 = qt * 64;

  const size_t rowbase = (size_t)(b * S) * D + h * DK;

  bh8 aq[2];
  {
    int qrow = qi0 + w * 16 + li;
#pragma unroll
    for (int ks = 0; ks < 2; ks++)
      aq[ks] = *(const bh8*)&qk[rowbase + (size_t)qrow * D + ks * 32 + lg * 8];
  }
  float frs[4];
#pragma unroll
  for (int rr = 0; rr < 4; rr++)
    frs[rr] = 0.125f * fr[b * S + qi0 + w * 16 + lg * 4 + rr];

  const fx4 zero = {0.f, 0.f, 0.f, 0.f};
  fx4 o_[4];
  float m_[4], l_[4];
#pragma unroll
  for (int i = 0; i < 4; i++) { o_[i] = zero; m_[i] = -1e30f; l_[i] = 0.f; }

  for (int kt = 0; kt <= qt; kt++) {
#pragma unroll
    for (int p = 0; p < 2; p++) {
      int c = p * 256 + tid;
      int r = c >> 3, g = c & 7;
      fx4 kvv = *(const fx4*)&qk[rowbase + (size_t)(kt * 64 + r) * D + g * 8];
      *(fx4*)&Kl[r * 64 + ((g ^ (r & 7)) * 8)] = kvv;
    }
    {
      int j = tid & 63, d0 = (tid >> 6) * 16;
      u16 tmp[16];
      *(fx4*)&tmp[0] = *(const fx4*)&vv[rowbase + (size_t)(kt * 64 + j) * D + d0];
      *(fx4*)&tmp[8] = *(const fx4*)&vv[rowbase + (size_t)(kt * 64 + j) * D + d0 + 8];
#pragma unroll
      for (int q = 0; q < 16; q++) Vt[(d0 + q) * 72 + j] = tmp[q];
    }
    __syncthreads();

    fx4 s[4];
#pragma unroll
    for (int jt = 0; jt < 4; jt++) s[jt] = zero;
#pragma unroll
    for (int ks = 0; ks < 2; ks++) {
      bh8 bk[4];
#pragma unroll
      for (int jt = 0; jt < 4; jt++) {
        int r = jt * 16 + li;
        bk[jt] = *(const bh8*)&Kl[r * 64 + (((ks * 4 + lg) ^ (r & 7)) * 8)];
      }
#pragma unroll
      for (int jt = 0; jt < 4; jt++)
        s[jt] = __builtin_amdgcn_mfma_f32_16x16x32_bf16(aq[ks], bk[jt], s[jt], 0, 0, 0);
    }

    const bool diag = (kt == qt);
#pragma unroll
    for (int jt = 0; jt < 4; jt++)
#pragma unroll
      for (int rr = 0; rr < 4; rr++) {
        float sv = s[jt][rr] * frs[rr];
        if (diag && (jt * 16 + li >= w * 16 + lg * 4 + rr)) sv = -1e30f;
        s[jt][rr] = sv;
      }

#pragma unroll
    for (int rr = 0; rr < 4; rr++) {
      float v0 = fmaxf(fmaxf(s[0][rr], s[1][rr]), fmaxf(s[2][rr], s[3][rr]));
      v0 = fmaxf(v0, __shfl_xor(v0, 1));
      v0 = fmaxf(v0, __shfl_xor(v0, 2));
      v0 = fmaxf(v0, __shfl_xor(v0, 4));
      v0 = fmaxf(v0, __shfl_xor(v0, 8));
      float mn = fmaxf(m_[rr], v0);
      float cf = __expf(m_[rr] - mn);
      m_[rr] = mn;
      float ps = 0.f;
#pragma unroll
      for (int jt = 0; jt < 4; jt++) {
        float e = __expf(s[jt][rr] - mn);
        s[jt][rr] = e;
        ps += e;
      }
      ps += __shfl_xor(ps, 1);
      ps += __shfl_xor(ps, 2);
      ps += __shfl_xor(ps, 4);
      ps += __shfl_xor(ps, 8);
      l_[rr] = l_[rr] * cf + ps;
#pragma unroll
      for (int dt = 0; dt < 4; dt++) o_[dt][rr] *= cf;
    }

#pragma unroll
    for (int jt = 0; jt < 4; jt++)
#pragma unroll
      for (int rr = 0; rr < 4; rr++)
        Pl[w][(lg * 4 + rr) * 72 + jt * 16 + li] = f2bf(s[jt][rr]);
    __syncthreads();

#pragma unroll
    for (int ks = 0; ks < 2; ks++) {
      bh8 pa = *(const bh8*)&Pl[w][li * 72 + ks * 32 + lg * 8];
      bh8 bvf[4];
#pragma unroll
      for (int dt = 0; dt < 4; dt++)
        bvf[dt] = *(const bh8*)&Vt[(dt * 16 + li) * 72 + ks * 32 + lg * 8];
#pragma unroll
      for (int dt = 0; dt < 4; dt++)
        o_[dt] = __builtin_amdgcn_mfma_f32_16x16x32_bf16(pa, bvf[dt], o_[dt], 0, 0, 0);
    }
    __syncthreads();
  }

#pragma unroll
  for (int rr = 0; rr < 4; rr++) {
    int rs = qi0 + w * 16 + lg * 4 + rr;
    float inv = (rs == 0) ? 0.f : 1.f / l_[rr];
#pragma unroll
    for (int dt = 0; dt < 4; dt++)
      att[rowbase + (size_t)rs * D + dt * 16 + li] = f2bf(o_[dt][rr] * inv);
  }
}

// ---------------- residual + LayerNorm (wave per row, 4 rows/block), proj in bf16 ----------------
__global__ __launch_bounds__(256) void add_ln(
    const float* __restrict__ xin, const u16* __restrict__ pb,
    const float* __restrict__ g, const float* __restrict__ bta,
    float* __restrict__ xout, u16* __restrict__ xb) {
  const int w = threadIdx.x >> 6, lane = threadIdx.x & 63;
  const int row = blockIdx.x * 4 + w;
  const float* xi = &xin[(size_t)row * D];
  const u16* pp = &pb[(size_t)row * D];

  float4 u0 = *(const float4*)&xi[lane * 4];
  float4 u1 = *(const float4*)&xi[256 + lane * 4];
  sh4 p0 = *(const sh4*)&pp[lane * 4];
  sh4 p1 = *(const sh4*)&pp[256 + lane * 4];
  float v[8] = {u0.x + bf2f((u16)p0.x), u0.y + bf2f((u16)p0.y),
                u0.z + bf2f((u16)p0.z), u0.w + bf2f((u16)p0.w),
                u1.x + bf2f((u16)p1.x), u1.y + bf2f((u16)p1.y),
                u1.z + bf2f((u16)p1.z), u1.w + bf2f((u16)p1.w)};

  float s = 0.f;
#pragma unroll
  for (int i = 0; i < 8; i++) s += v[i];
#pragma unroll
  for (int d = 1; d < 64; d <<= 1) s += __shfl_xor(s, d);
  const float mu = s * (1.0f / D);

  float vs = 0.f;
#pragma unroll
  for (int i = 0; i < 8; i++) { v[i] -= mu; vs += v[i] * v[i]; }
#pragma unroll
  for (int d = 1; d < 64; d <<= 1) vs += __shfl_xor(vs, d);
  const float rs = rsqrtf(vs * (1.0f / D) + 1e-5f);

  float4 g0 = *(const float4*)&g[lane * 4];
  float4 b0 = *(const float4*)&bta[lane * 4];
  float4 g1 = *(const float4*)&g[256 + lane * 4];
  float4 b1 = *(const float4*)&bta[256 + lane * 4];
  float o[8];
  o[0] = v[0] * rs * g0.x + b0.x; o[1] = v[1] * rs * g0.y + b0.y;
  o[2] = v[2] * rs * g0.z + b0.z; o[3] = v[3] * rs * g0.w + b0.w;
  o[4] = v[4] * rs * g1.x + b1.x; o[5] = v[5] * rs * g1.y + b1.y;
  o[6] = v[6] * rs * g1.z + b1.z; o[7] = v[7] * rs * g1.w + b1.w;

  *(float4*)&xout[(size_t)row * D + lane * 4] = *(float4*)&o[0];
  *(float4*)&xout[(size_t)row * D + 256 + lane * 4] = *(float4*)&o[4];
  if (xb) {
    u16 ob[8];
#pragma unroll
    for (int i = 0; i < 8; i++) ob[i] = f2bf(o[i]);
    *(sh4*)&xb[(size_t)row * D + lane * 4] = *(sh4*)&ob[0];
    *(sh4*)&xb[(size_t)row * D + 256 + lane * 4] = *(sh4*)&ob[4];
  }
}

extern "C" void kernel_launch(void* const* d_in, const int* in_sizes, int n_in,
                              void* d_out, int out_size, void* d_ws, size_t ws_size,
                              hipStream_t stream) {
  const float* q_embed = (const float*)d_in[0];
  const float* qa_embed = (const float*)d_in[1];
  const float* forget_rate = (const float*)d_in[2];
  const float* pe = (const float*)d_in[3];
  const float* Wk = (const float*)d_in[4];
  const float* bk = (const float*)d_in[5];
  const float* Wv = (const float*)d_in[6];
  const float* bv = (const float*)d_in[7];
  const float* Wo = (const float*)d_in[8];
  const float* bo = (const float*)d_in[9];
  const float* ln1_g = (const float*)d_in[10];
  const float* ln1_b = (const float*)d_in[11];
  const float* W1 = (const float*)d_in[12];
  const float* b1 = (const float*)d_in[13];
  const float* W2 = (const float*)d_in[14];
  const float* b2 = (const float*)d_in[15];
  const float* ln2_g = (const float*)d_in[16];
  const float* ln2_b = (const float*)d_in[17];

  const size_t nMD = (size_t)M * D;
  char* p = (char*)d_ws;
  float* x = (float*)p;      p += nMD * 4;
  u16* projb = (u16*)p;      p += nMD * 2;
  u16* xb = (u16*)p;         p += nMD * 2;
  u16* yb = (u16*)p;         p += nMD * 2;
  u16* qkb = (u16*)p;        p += nMD * 2;
  u16* vvb = (u16*)p;        p += nMD * 2;
  u16* attb = (u16*)p;       p += nMD * 2;
  u16* hb = (u16*)p;         p += (size_t)M * DFF * 2;
  u16* Wkt = (u16*)p;        p += (size_t)NL * D * D * 2;
  u16* Wvt = (u16*)p;        p += (size_t)NL * D * D * 2;
  u16* Wot = (u16*)p;        p += (size_t)NL * D * D * 2;
  u16* W1t = (u16*)p;        p += (size_t)NL * D * DFF * 2;
  u16* W2t = (u16*)p;        p += (size_t)NL * DFF * D * 2;

  add_pe<<<(B * S * D) / 256, 256, 0, stream>>>(q_embed, qa_embed, pe, x, xb, yb);
  transpose_cvt<<<dim3(D / 64, D / 64, NL), 256, 0, stream>>>(Wk, Wkt, D, D);
  transpose_cvt<<<dim3(D / 64, D / 64, NL), 256, 0, stream>>>(Wv, Wvt, D, D);
  transpose_cvt<<<dim3(D / 64, D / 64, NL), 256, 0, stream>>>(Wo, Wot, D, D);
  transpose_cvt<<<dim3(DFF / 64, D / 64, NL), 256, 0, stream>>>(W1, W1t, D, DFF);
  transpose_cvt<<<dim3(D / 64, DFF / 64, NL), 256, 0, stream>>>(W2, W2t, DFF, D);

  const int gD = (M / 64) * (D / 128);       // 512
  const int gF = (M / 128) * (DFF / 128);    // 1024

  for (int l = 0; l < NL; l++) {
    gemm2_dual<<<dim3(gD, 2), 256, 0, stream>>>(
        xb, Wkt + (size_t)l * D * D, bk + l * D, qkb,
        yb, Wvt + (size_t)l * D * D, bv + l * D, vvb, D, D, D / 128);
    attn_mfma<<<dim3(B * H, S / 64), 256, 0, stream>>>(qkb, vvb, forget_rate, attb);
    gemm2<64, 128, 0, 1><<<gD, 256, 0, stream>>>(
        attb, Wot + (size_t)l * D * D, bo + l * D, projb, D, D, D / 128);
    add_ln<<<M / 4, 256, 0, stream>>>(x, projb, ln1_g + l * D, ln1_b + l * D, x, xb);
    gemm2<128, 128, 1, 1><<<gF, 256, 0, stream>>>(
        xb, W1t + (size_t)l * D * DFF, b1 + l * DFF, hb, DFF, D, DFF / 128);
    gemm2<64, 128, 0, 1><<<gD, 256, 0, stream>>>(
        hb, W2t + (size_t)l * DFF * D, b2 + l * D, projb, D, DFF, D / 128);
    float* xo = (l == NL - 1) ? (float*)d_out : x;
    u16* xbo = (l == NL - 1) ? (u16*)nullptr : xb;
    add_ln<<<M / 4, 256, 0, stream>>>(x, projb, ln2_g + l * D, ln2_b + l * D, xo, xbo);
  }
}